// Round 1
// baseline (1782.647 us; speedup 1.0000x reference)
//
#include <hip/hip_runtime.h>
#include <math.h>

#define TOKENS 8192
#define DDIM 1024
#define FDIM 4096
#define NEXP 8
#define CAP 8192
#define TK 32            // K-slab per pipeline stage
#define BM1 256
#define BN1 128
#define NT1 (DDIM / TK)  // 32
#define BM2 256
#define BN2 256
#define NT2 (FDIM / TK)  // 128

typedef __bf16 bf16x8 __attribute__((ext_vector_type(8)));
typedef float f32x4 __attribute__((ext_vector_type(4)));

__device__ __forceinline__ unsigned short f2bf(float f) {
  union { float f; unsigned int u; } v; v.f = f;
  unsigned int u = v.u;
  return (unsigned short)((u + 0x7FFFu + ((u >> 16) & 1u)) >> 16);
}
__device__ __forceinline__ float bf2f(unsigned short h) {
  union { unsigned int u; float f; } v; v.u = ((unsigned int)h) << 16;
  return v.f;
}

__device__ __forceinline__ void load_lds16(const void* g, void* l) {
  __builtin_amdgcn_global_load_lds(
      (const __attribute__((address_space(1))) void*)g,
      (__attribute__((address_space(3))) void*)l, 16, 0, 0);
}

// counted-vmcnt pipeline primitives: raw barrier (NO vmcnt(0)+lgkmcnt(0) drain),
// memory-clobber fences pin code motion around the barrier.
#define VMW(n) asm volatile("s_waitcnt vmcnt(" #n ")" ::: "memory")
#define BARRIER() do { __builtin_amdgcn_s_barrier(); asm volatile("" ::: "memory"); } while (0)

// ---------------- weight transpose+convert: [E][R][C] fp32 -> [E][C][R] bf16 ----------------
__global__ void k_tconv(const float* __restrict__ in, unsigned short* __restrict__ out,
                        int R, int C) {
  __shared__ float tile[32][132];
  size_t mat = (size_t)R * C;
  const float* src = in + (size_t)blockIdx.z * mat;
  unsigned short* dst = out + (size_t)blockIdx.z * mat;
  int c0 = blockIdx.x * 128, r0 = blockIdx.y * 32;
  int t = threadIdx.x;
#pragma unroll
  for (int i = 0; i < 4; ++i) {
    int idx = i * 1024 + t * 4;
    int r = idx >> 7, c = idx & 127;
    float4 v = *(const float4*)(src + (size_t)(r0 + r) * C + (c0 + c));
    *(float4*)&tile[r][c] = v;
  }
  __syncthreads();
#pragma unroll
  for (int i = 0; i < 4; ++i) {
    int idx = i * 1024 + t * 4;
    int c = idx >> 5, r = idx & 31;
    ushort4 o;
    o.x = f2bf(tile[r + 0][c]);
    o.y = f2bf(tile[r + 1][c]);
    o.z = f2bf(tile[r + 2][c]);
    o.w = f2bf(tile[r + 3][c]);
    *(ushort4*)(dst + (size_t)(c0 + c) * R + (r0 + r)) = o;
  }
}

// ---------------- gating (also emits xb = bf16(x)) ----------------

__global__ void k_zero(int* __restrict__ counts) {
  if (threadIdx.x < NEXP) counts[threadIdx.x] = 0;
}

__global__ void k_gate(const float* __restrict__ x, const float* __restrict__ gw,
                       unsigned short* __restrict__ xb,
                       int* __restrict__ counts, int* __restrict__ tok_list,
                       float* __restrict__ wgt_list, int* __restrict__ tok_slot) {
  int wave = threadIdx.x >> 6, lane = threadIdx.x & 63;
  int t = blockIdx.x * 4 + wave;
  const float* xr = x + (size_t)t * DDIM;
  unsigned short* xbr = xb + (size_t)t * DDIM;
  float acc[NEXP];
#pragma unroll
  for (int e = 0; e < NEXP; ++e) acc[e] = 0.f;
  for (int d = lane; d < DDIM; d += 64) {
    float xv = xr[d];
    xbr[d] = f2bf(xv);
    const float* g = gw + d * NEXP;
#pragma unroll
    for (int e = 0; e < NEXP; ++e) acc[e] += xv * g[e];
  }
#pragma unroll
  for (int e = 0; e < NEXP; ++e) {
#pragma unroll
    for (int off = 32; off > 0; off >>= 1) acc[e] += __shfl_down(acc[e], off, 64);
  }
  if (lane == 0) {
    int e0 = 0; float v0 = acc[0];
#pragma unroll
    for (int e = 1; e < NEXP; ++e) if (acc[e] > v0) { v0 = acc[e]; e0 = e; }
    int e1 = -1; float v1 = -3.0e38f;
#pragma unroll
    for (int e = 0; e < NEXP; ++e) if (e != e0 && acc[e] > v1) { v1 = acc[e]; e1 = e; }
    float p1 = expf(v1 - v0);
    float s = 1.0f + p1;
    float w0 = 1.0f / s, w1 = p1 / s;
    int pos0 = atomicAdd(&counts[e0], 1);
    tok_list[e0 * CAP + pos0] = t;
    wgt_list[e0 * CAP + pos0] = w0;
    tok_slot[t * 2 + 0] = e0 * CAP + pos0;
    int pos1 = atomicAdd(&counts[e1], 1);
    tok_list[e1 * CAP + pos1] = t;
    wgt_list[e1 * CAP + pos1] = w1;
    tok_slot[t * 2 + 1] = e1 * CAP + pos1;
  }
}

__global__ void k_scan(const int* __restrict__ counts, int* __restrict__ bases) {
  if (threadIdx.x == 0) {
    int s = 0;
    for (int e = 0; e < NEXP; ++e) { bases[e] = s; s += counts[e]; }
  }
}

// LDS layout per K=32 slab: row stride 32 ushorts (64 B) = 4 chunks of 16 B;
// logical chunk c of row r stored at position c ^ (r & 3) (linear global_load_lds dest,
// inverse-swizzled global source, swizzled frag read — both-sides-or-neither).
// Frag read (16x16x32, lane fr,fq): addr = row*32 + ((fq ^ (fr&3)) * 8) ushorts.

// ---------------- GEMM1: H = silu(X@wi0) * (X@wi1) ----------------
// 512 threads, BM=256 x BN=128, dual-B, 4-slot ring pipeline, vmcnt(8) steady state.
// XCD decode: 8 nt-blocks sharing (e,mt) A-slab per XCD.

__global__ __launch_bounds__(512, 2) void k_gemm1(
    const unsigned short* __restrict__ xb, const unsigned short* __restrict__ w0t,
    const unsigned short* __restrict__ w1t, const int* __restrict__ counts,
    const int* __restrict__ bases, const int* __restrict__ tok_list,
    unsigned short* __restrict__ H) {
  int b = blockIdx.x;
  int xcd = b & 7, j = b >> 3;
  int i8 = j & 7, grp = j >> 3;        // grp 0..127
  int G = grp * 8 + xcd;               // 0..1023
  int e = G >> 7;
  int mt = (G >> 2) & 31;
  int nt = ((G & 3) << 3) | i8;        // 0..31

  int cnt = counts[e];
  int m0 = mt * BM1;
  if (m0 >= cnt) return;
  int mv = min(BM1, cnt - m0);
  int gbase = bases[e] + m0;

  __shared__ __align__(16) unsigned short As[4][BM1 * TK];   // 4 x 16 KB
  __shared__ __align__(16) unsigned short B0s[4][BN1 * TK];  // 4 x 8 KB
  __shared__ __align__(16) unsigned short B1s[4][BN1 * TK];  // 4 x 8 KB
  __shared__ int toks[BM1];

  int t = threadIdx.x;
  if (t < BM1) toks[t] = tok_list[e * CAP + m0 + min(t, mv - 1)];
  __syncthreads();

  int wid = t >> 6, lane = t & 63;
  int wm = (wid >> 1) * 64, wn = (wid & 1) * 64;   // 4M x 2N waves, 64x64 tile each
  int fr = lane & 15, fq = lane >> 4;
  int co = (fq ^ (fr & 3)) * 8;

  const unsigned short* b0p = w0t + ((size_t)e * FDIM + (size_t)nt * BN1) * DDIM;
  const unsigned short* b1p = w1t + ((size_t)e * FDIM + (size_t)nt * BN1) * DDIM;

  // staging descriptors: A = 2 rounds (s = t, t+512), B0/B1 = 1 round each
  const unsigned short *srcA0, *srcA1;
  int ldsA0, ldsA1;
  {
    int s0 = t, s1 = t + 512;
    int r0 = s0 >> 2, r1 = s1 >> 2;
    srcA0 = xb + (size_t)toks[r0] * DDIM + ((s0 & 3) ^ (r0 & 3)) * 8;
    srcA1 = xb + (size_t)toks[r1] * DDIM + ((s1 & 3) ^ (r1 & 3)) * 8;
    ldsA0 = s0 * 8; ldsA1 = s1 * 8;
  }
  int rb = t >> 2;
  int sbo = ((t & 3) ^ (rb & 3)) * 8;
  const unsigned short* srcB0 = b0p + (size_t)rb * DDIM + sbo;
  const unsigned short* srcB1 = b1p + (size_t)rb * DDIM + sbo;
  int ldsB = t * 8;

  f32x4 acc0[4][4], acc1[4][4];
#pragma unroll
  for (int mi = 0; mi < 4; ++mi)
#pragma unroll
    for (int ni = 0; ni < 4; ++ni)
#pragma unroll
      for (int r = 0; r < 4; ++r) { acc0[mi][ni][r] = 0.f; acc1[mi][ni][r] = 0.f; }

#define STAGE1(kt, sl) do { int c_ = (kt) * TK;          \
    load_lds16(srcA0 + c_, &As[sl][ldsA0]);              \
    load_lds16(srcA1 + c_, &As[sl][ldsA1]);              \
    load_lds16(srcB0 + c_, &B0s[sl][ldsB]);              \
    load_lds16(srcB1 + c_, &B1s[sl][ldsB]); } while (0)

#define COMPUTE1(sl) do {                                                   \
    const unsigned short* ap = As[sl];                                      \
    const unsigned short* q0 = B0s[sl];                                     \
    const unsigned short* q1 = B1s[sl];                                     \
    bf16x8 a[4], p0[4], p1[4];                                              \
    _Pragma("unroll") for (int mi = 0; mi < 4; ++mi)                        \
      a[mi] = *(const bf16x8*)(ap + (wm + mi * 16 + fr) * TK + co);         \
    _Pragma("unroll") for (int ni = 0; ni < 4; ++ni) {                      \
      p0[ni] = *(const bf16x8*)(q0 + (wn + ni * 16 + fr) * TK + co);        \
      p1[ni] = *(const bf16x8*)(q1 + (wn + ni * 16 + fr) * TK + co); }      \
    __builtin_amdgcn_s_setprio(1);                                          \
    _Pragma("unroll") for (int mi = 0; mi < 4; ++mi)                        \
      _Pragma("unroll") for (int ni = 0; ni < 4; ++ni) {                    \
        acc0[mi][ni] = __builtin_amdgcn_mfma_f32_16x16x32_bf16(a[mi], p0[ni], acc0[mi][ni], 0, 0, 0); \
        acc1[mi][ni] = __builtin_amdgcn_mfma_f32_16x16x32_bf16(a[mi], p1[ni], acc1[mi][ni], 0, 0, 0); } \
    __builtin_amdgcn_s_setprio(0); } while (0)

  // prologue: 3 slabs in flight (12 VMEM per thread)
  STAGE1(0, 0); STAGE1(1, 1); STAGE1(2, 2);
  for (int kt = 0; kt < NT1 - 3; ++kt) {
    VMW(8);            // tile kt landed; kt+1,kt+2 (8 loads) stay in flight
    BARRIER();
    STAGE1(kt + 3, (kt + 3) & 3);   // overwrites slot read at kt-1: safe past barrier
    COMPUTE1(kt & 3);
  }
  VMW(8); BARRIER(); COMPUTE1((NT1 - 3) & 3);
  VMW(4); BARRIER(); COMPUTE1((NT1 - 2) & 3);
  VMW(0); BARRIER(); COMPUTE1((NT1 - 1) & 3);
#undef STAGE1
#undef COMPUTE1

  int n0 = nt * BN1 + wn;
#pragma unroll
  for (int mi = 0; mi < 4; ++mi) {
    int mloc = wm + mi * 16 + fq * 4;
#pragma unroll
    for (int ni = 0; ni < 4; ++ni) {
      int col = n0 + ni * 16 + fr;
#pragma unroll
      for (int r = 0; r < 4; ++r) {
        int mrow = mloc + r;
        if (mrow < mv) {
          float g = acc0[mi][ni][r];
          float hv = (g / (1.0f + expf(-g))) * acc1[mi][ni][r];
          H[(size_t)(gbase + mrow) * FDIM + col] = f2bf(hv);
        }
      }
    }
  }
}

// ---------------- GEMM2: O = H @ wo^T(stored [D][F]) ----------------
// 512 threads, BM=256 x BN=256, 4-slot ring, vmcnt(8) steady. 8 waves 2M x 4N,
// per-wave 128x64. XCD decode: 8 mt-blocks sharing (e,nt) B-slab per XCD.

__global__ __launch_bounds__(512, 2) void k_gemm2(
    const unsigned short* __restrict__ H, const unsigned short* __restrict__ wot,
    const int* __restrict__ counts, const int* __restrict__ bases,
    unsigned short* __restrict__ O) {
  int b = blockIdx.x;
  int xcd = b & 7, j = b >> 3;
  int i8 = j & 7, grp = j >> 3;        // grp 0..15
  int G = grp * 8 + xcd;               // 0..127
  int e = G >> 4;
  int nt = (G >> 2) & 3;
  int mt = ((G & 3) << 3) | i8;        // 0..31

  int cnt = counts[e];
  int m0 = mt * BM2;
  if (m0 >= cnt) return;
  int mv = min(BM2, cnt - m0);
  int gbase = bases[e] + m0;

  __shared__ __align__(16) unsigned short As[4][BM2 * TK];   // 4 x 16 KB
  __shared__ __align__(16) unsigned short Bs[4][BN2 * TK];   // 4 x 16 KB

  int t = threadIdx.x;
  int wid = t >> 6, lane = t & 63;
  int wm = (wid >> 2) * 128, wn = (wid & 3) * 64;
  int fr = lane & 15, fq = lane >> 4;
  int co = (fq ^ (fr & 3)) * 8;

  const unsigned short* bp = wot + ((size_t)e * DDIM + (size_t)nt * BN2) * FDIM;

  const unsigned short *srcA0, *srcA1, *srcB0, *srcB1;
  int ldsA0, ldsA1, ldsB0, ldsB1;
  {
    int s0 = t, s1 = t + 512;
    int r0 = s0 >> 2, r1 = s1 >> 2;
    int o0 = ((s0 & 3) ^ (r0 & 3)) * 8, o1 = ((s1 & 3) ^ (r1 & 3)) * 8;
    srcA0 = H + (size_t)(gbase + min(r0, mv - 1)) * FDIM + o0;
    srcA1 = H + (size_t)(gbase + min(r1, mv - 1)) * FDIM + o1;
    srcB0 = bp + (size_t)r0 * FDIM + o0;
    srcB1 = bp + (size_t)r1 * FDIM + o1;
    ldsA0 = s0 * 8; ldsA1 = s1 * 8;
    ldsB0 = s0 * 8; ldsB1 = s1 * 8;
  }

  f32x4 acc[8][4];
#pragma unroll
  for (int mi = 0; mi < 8; ++mi)
#pragma unroll
    for (int ni = 0; ni < 4; ++ni)
#pragma unroll
      for (int r = 0; r < 4; ++r) acc[mi][ni][r] = 0.f;

#define STAGE2(kt, sl) do { int c_ = (kt) * TK;          \
    load_lds16(srcA0 + c_, &As[sl][ldsA0]);              \
    load_lds16(srcA1 + c_, &As[sl][ldsA1]);              \
    load_lds16(srcB0 + c_, &Bs[sl][ldsB0]);              \
    load_lds16(srcB1 + c_, &Bs[sl][ldsB1]); } while (0)

#define COMPUTE2(sl) do {                                                   \
    const unsigned short* ap = As[sl];                                      \
    const unsigned short* qp = Bs[sl];                                      \
    bf16x8 a[8], p[4];                                                      \
    _Pragma("unroll") for (int mi = 0; mi < 8; ++mi)                        \
      a[mi] = *(const bf16x8*)(ap + (wm + mi * 16 + fr) * TK + co);         \
    _Pragma("unroll") for (int ni = 0; ni < 4; ++ni)                        \
      p[ni] = *(const bf16x8*)(qp + (wn + ni * 16 + fr) * TK + co);         \
    __builtin_amdgcn_s_setprio(1);                                          \
    _Pragma("unroll") for (int mi = 0; mi < 8; ++mi)                        \
      _Pragma("unroll") for (int ni = 0; ni < 4; ++ni)                      \
        acc[mi][ni] = __builtin_amdgcn_mfma_f32_16x16x32_bf16(a[mi], p[ni], acc[mi][ni], 0, 0, 0); \
    __builtin_amdgcn_s_setprio(0); } while (0)

  STAGE2(0, 0); STAGE2(1, 1); STAGE2(2, 2);
  for (int kt = 0; kt < NT2 - 3; ++kt) {
    VMW(8);
    BARRIER();
    STAGE2(kt + 3, (kt + 3) & 3);
    COMPUTE2(kt & 3);
  }
  VMW(8); BARRIER(); COMPUTE2((NT2 - 3) & 3);
  VMW(4); BARRIER(); COMPUTE2((NT2 - 2) & 3);
  VMW(0); BARRIER(); COMPUTE2((NT2 - 1) & 3);
#undef STAGE2
#undef COMPUTE2

  int n0 = nt * BN2 + wn;
#pragma unroll
  for (int mi = 0; mi < 8; ++mi) {
    int mloc = wm + mi * 16 + fq * 4;
#pragma unroll
    for (int ni = 0; ni < 4; ++ni) {
      int col = n0 + ni * 16 + fr;
#pragma unroll
      for (int r = 0; r < 4; ++r) {
        int mrow = mloc + r;
        if (mrow < mv)
          O[(size_t)(gbase + mrow) * DDIM + col] = f2bf(acc[mi][ni][r]);
      }
    }
  }
}

// ---------------- combine ----------------

__global__ void k_combine(const unsigned short* __restrict__ O, const int* __restrict__ bases,
                          const int* __restrict__ tok_slot, const float* __restrict__ wgt_list,
                          float* __restrict__ out) {
  int t = blockIdx.x;
  int s0 = tok_slot[t * 2 + 0];
  int s1 = tok_slot[t * 2 + 1];
  int g0 = bases[s0 / CAP] + (s0 & (CAP - 1));
  int g1 = bases[s1 / CAP] + (s1 & (CAP - 1));
  float w0 = wgt_list[s0], w1 = wgt_list[s1];
  int d = threadIdx.x * 4;
  ushort4 a = *(const ushort4*)(O + (size_t)g0 * DDIM + d);
  ushort4 b = *(const ushort4*)(O + (size_t)g1 * DDIM + d);
  float4 r;
  r.x = w0 * bf2f(a.x) + w1 * bf2f(b.x);
  r.y = w0 * bf2f(a.y) + w1 * bf2f(b.y);
  r.z = w0 * bf2f(a.z) + w1 * bf2f(b.z);
  r.w = w0 * bf2f(a.w) + w1 * bf2f(b.w);
  *(float4*)(out + (size_t)t * DDIM + d) = r;
}

// ---------------- launch ----------------

extern "C" void kernel_launch(void* const* d_in, const int* in_sizes, int n_in,
                              void* d_out, int out_size, void* d_ws, size_t ws_size,
                              hipStream_t stream) {
  const float* x   = (const float*)d_in[0];
  const float* gw  = (const float*)d_in[1];
  const float* wi0 = (const float*)d_in[2];
  const float* wi1 = (const float*)d_in[3];
  const float* wo  = (const float*)d_in[4];
  float* out = (float*)d_out;

  char* p = (char*)d_ws;
  unsigned short* xb  = (unsigned short*)p; p += (size_t)TOKENS * DDIM * 2;
  unsigned short* w0t = (unsigned short*)p; p += (size_t)NEXP * FDIM * DDIM * 2;
  unsigned short* w1t = (unsigned short*)p; p += (size_t)NEXP * FDIM * DDIM * 2;
  unsigned short* wot = (unsigned short*)p; p += (size_t)NEXP * DDIM * FDIM * 2;
  unsigned short* H   = (unsigned short*)p; p += (size_t)2 * TOKENS * FDIM * 2;
  unsigned short* O   = (unsigned short*)p; p += (size_t)2 * TOKENS * DDIM * 2;
  int*   counts   = (int*)p; p += 256;
  int*   bases    = (int*)p; p += 256;
  int*   tok_list = (int*)p; p += (size_t)NEXP * CAP * 4;
  float* wgt_list = (float*)p; p += (size_t)NEXP * CAP * 4;
  int*   tok_slot = (int*)p; p += (size_t)TOKENS * 2 * 4;

  // weight transpose+convert
  k_tconv<<<dim3(FDIM / 128, DDIM / 32, NEXP), 256, 0, stream>>>(wi0, w0t, DDIM, FDIM);
  k_tconv<<<dim3(FDIM / 128, DDIM / 32, NEXP), 256, 0, stream>>>(wi1, w1t, DDIM, FDIM);
  k_tconv<<<dim3(DDIM / 128, FDIM / 32, NEXP), 256, 0, stream>>>(wo, wot, FDIM, DDIM);

  // gating + routing (also emits xb)
  k_zero<<<1, 64, 0, stream>>>(counts);
  k_gate<<<TOKENS / 4, 256, 0, stream>>>(x, gw, xb, counts, tok_list, wgt_list, tok_slot);
  k_scan<<<1, 64, 0, stream>>>(counts, bases);

  // expert MLP (ring-pipelined, counted-vmcnt GEMMs)
  k_gemm1<<<NEXP * (CAP / BM1) * (FDIM / BN1), 512, 0, stream>>>(xb, w0t, w1t, counts, bases, tok_list, H);
  k_gemm2<<<NEXP * (CAP / BM2) * (DDIM / BN2), 512, 0, stream>>>(H, wot, counts, bases, O);

  // weighted combine
  k_combine<<<TOKENS, 256, 0, stream>>>(O, bases, tok_slot, wgt_list, out);
}

// Round 3
// 1437.314 us; speedup vs baseline: 1.2403x; 1.2403x over previous
//
#include <hip/hip_runtime.h>
#include <math.h>

#define TOKENS 8192
#define DDIM 1024
#define FDIM 4096
#define NEXP 8
#define CAP 8192
#define BM 128
#define BN 128
#define BK 64            // 8 chunks of 16B per row — proven 0-conflict swizzle
#define NT1 (DDIM / BK)  // 16
#define NT2 (FDIM / BK)  // 64

typedef __bf16 bf16x8 __attribute__((ext_vector_type(8)));
typedef float f32x4 __attribute__((ext_vector_type(4)));

__device__ __forceinline__ unsigned short f2bf(float f) {
  union { float f; unsigned int u; } v; v.f = f;
  unsigned int u = v.u;
  return (unsigned short)((u + 0x7FFFu + ((u >> 16) & 1u)) >> 16);
}
__device__ __forceinline__ float bf2f(unsigned short h) {
  union { unsigned int u; float f; } v; v.u = ((unsigned int)h) << 16;
  return v.f;
}

__device__ __forceinline__ void load_lds16(const void* g, void* l) {
  __builtin_amdgcn_global_load_lds(
      (const __attribute__((address_space(1))) void*)g,
      (__attribute__((address_space(3))) void*)l, 16, 0, 0);
}

// counted-vmcnt pipeline primitives. VMW must precede BARRIER: per-wave vmcnt
// guarantees THIS wave's slab loads landed; the barrier then makes all waves'
// loads globally visible before any ds_read of the slot.
#define VMW(n) asm volatile("s_waitcnt vmcnt(" #n ")" ::: "memory")
#define BARRIER() do { asm volatile("" ::: "memory"); \
                       __builtin_amdgcn_s_barrier();  \
                       asm volatile("" ::: "memory"); } while (0)

// ---------------- weight transpose+convert: [E][R][C] fp32 -> [E][C][R] bf16 ----------------
__global__ void k_tconv(const float* __restrict__ in, unsigned short* __restrict__ out,
                        int R, int C) {
  __shared__ float tile[32][132];
  size_t mat = (size_t)R * C;
  const float* src = in + (size_t)blockIdx.z * mat;
  unsigned short* dst = out + (size_t)blockIdx.z * mat;
  int c0 = blockIdx.x * 128, r0 = blockIdx.y * 32;
  int t = threadIdx.x;
#pragma unroll
  for (int i = 0; i < 4; ++i) {
    int idx = i * 1024 + t * 4;
    int r = idx >> 7, c = idx & 127;
    float4 v = *(const float4*)(src + (size_t)(r0 + r) * C + (c0 + c));
    *(float4*)&tile[r][c] = v;
  }
  __syncthreads();
#pragma unroll
  for (int i = 0; i < 4; ++i) {
    int idx = i * 1024 + t * 4;
    int c = idx >> 5, r = idx & 31;
    ushort4 o;
    o.x = f2bf(tile[r + 0][c]);
    o.y = f2bf(tile[r + 1][c]);
    o.z = f2bf(tile[r + 2][c]);
    o.w = f2bf(tile[r + 3][c]);
    *(ushort4*)(dst + (size_t)(c0 + c) * R + (r0 + r)) = o;
  }
}

// ---------------- gating (also emits xb = bf16(x)) ----------------

__global__ void k_zero(int* __restrict__ counts) {
  if (threadIdx.x < NEXP) counts[threadIdx.x] = 0;
}

__global__ void k_gate(const float* __restrict__ x, const float* __restrict__ gw,
                       unsigned short* __restrict__ xb,
                       int* __restrict__ counts, int* __restrict__ tok_list,
                       float* __restrict__ wgt_list, int* __restrict__ tok_slot) {
  int wave = threadIdx.x >> 6, lane = threadIdx.x & 63;
  int t = blockIdx.x * 4 + wave;
  const float* xr = x + (size_t)t * DDIM;
  unsigned short* xbr = xb + (size_t)t * DDIM;
  float acc[NEXP];
#pragma unroll
  for (int e = 0; e < NEXP; ++e) acc[e] = 0.f;
  for (int d = lane; d < DDIM; d += 64) {
    float xv = xr[d];
    xbr[d] = f2bf(xv);
    const float* g = gw + d * NEXP;
#pragma unroll
    for (int e = 0; e < NEXP; ++e) acc[e] += xv * g[e];
  }
#pragma unroll
  for (int e = 0; e < NEXP; ++e) {
#pragma unroll
    for (int off = 32; off > 0; off >>= 1) acc[e] += __shfl_down(acc[e], off, 64);
  }
  if (lane == 0) {
    int e0 = 0; float v0 = acc[0];
#pragma unroll
    for (int e = 1; e < NEXP; ++e) if (acc[e] > v0) { v0 = acc[e]; e0 = e; }
    int e1 = -1; float v1 = -3.0e38f;
#pragma unroll
    for (int e = 0; e < NEXP; ++e) if (e != e0 && acc[e] > v1) { v1 = acc[e]; e1 = e; }
    float p1 = expf(v1 - v0);
    float s = 1.0f + p1;
    float w0 = 1.0f / s, w1 = p1 / s;
    int pos0 = atomicAdd(&counts[e0], 1);
    tok_list[e0 * CAP + pos0] = t;
    wgt_list[e0 * CAP + pos0] = w0;
    tok_slot[t * 2 + 0] = e0 * CAP + pos0;
    int pos1 = atomicAdd(&counts[e1], 1);
    tok_list[e1 * CAP + pos1] = t;
    wgt_list[e1 * CAP + pos1] = w1;
    tok_slot[t * 2 + 1] = e1 * CAP + pos1;
  }
}

__global__ void k_scan(const int* __restrict__ counts, int* __restrict__ bases) {
  if (threadIdx.x == 0) {
    int s = 0;
    for (int e = 0; e < NEXP; ++e) { bases[e] = s; s += counts[e]; }
  }
}

// LDS layout per slot (BK=64): row stride 64 ushorts (128 B); logical 16B-chunk c of
// row r stored at position c ^ (r & 7).  Staging slot s: row=s>>3, pos=s&7,
// logical chunk = (s&7) ^ (row&7).  Fragment read (16x16x32 step kh, lane fr,fq):
// offset = row*64 + (((kh<<2)|fq) ^ (fr&7))*8 ushorts.  Measured 0 conflicts (round 0).

// ---------------- GEMM1: H = silu(X@wi0) * (X@wi1) ----------------
// 512 thr / 8 waves (2M x 4N, 64x32 per wave, dual acc). 3-slot LDS ring (144 KB),
// prefetch depth 2 (coverage ~2480 cyc/CU > HBM latency), vmcnt(6) counted waits.

__global__ __launch_bounds__(512, 2) void k_gemm1(
    const unsigned short* __restrict__ xb, const unsigned short* __restrict__ w0t,
    const unsigned short* __restrict__ w1t, const int* __restrict__ counts,
    const int* __restrict__ bases, const int* __restrict__ tok_list,
    unsigned short* __restrict__ H) {
  int b = blockIdx.x;
  int xcd = b & 7, j = b >> 3;
  int i8 = j & 7, grp = j >> 3;
  int G = grp * 8 + xcd;               // 0..2047
  int e = G >> 8;
  int mt = (G >> 2) & 63;
  int nt = ((G & 3) << 3) | i8;        // 0..31

  int cnt = counts[e];
  int m0 = mt * BM;
  if (m0 >= cnt) return;
  int mv = min(BM, cnt - m0);
  int gbase = bases[e] + m0;

  __shared__ __align__(16) unsigned short As[3][BM * BK];
  __shared__ __align__(16) unsigned short B0s[3][BM * BK];
  __shared__ __align__(16) unsigned short B1s[3][BM * BK];
  __shared__ int toks[BM];

  int t = threadIdx.x;
  if (t < BM) toks[t] = tok_list[e * CAP + m0 + min(t, mv - 1)];
  __syncthreads();

  int wid = t >> 6, lane = t & 63;
  int wm = (wid >> 2) * 64, wn = (wid & 3) * 32;
  int fr = lane & 15, fq = lane >> 4;
  int sw = fr & 7;
  int co0 = (fq ^ sw) * 8;
  int co1 = ((4 | fq) ^ sw) * 8;

  const unsigned short* b0p = w0t + ((size_t)e * FDIM + (size_t)nt * BN) * DDIM;
  const unsigned short* b1p = w1t + ((size_t)e * FDIM + (size_t)nt * BN) * DDIM;

  // staging: 2 rounds per matrix (128 rows x 8 chunks = 1024 slots / 512 thr)
  int s0 = t, s1 = t + 512;
  int r0 = s0 >> 3, r1 = s1 >> 3;
  int o0 = ((s0 & 7) ^ (r0 & 7)) * 8, o1 = ((s1 & 7) ^ (r1 & 7)) * 8;
  const unsigned short* pA0 = xb + (size_t)toks[r0] * DDIM + o0;
  const unsigned short* pA1 = xb + (size_t)toks[r1] * DDIM + o1;
  const unsigned short* pB00 = b0p + (size_t)r0 * DDIM + o0;
  const unsigned short* pB01 = b0p + (size_t)r1 * DDIM + o1;
  const unsigned short* pB10 = b1p + (size_t)r0 * DDIM + o0;
  const unsigned short* pB11 = b1p + (size_t)r1 * DDIM + o1;

  f32x4 acc0[4][2], acc1[4][2];
#pragma unroll
  for (int mi = 0; mi < 4; ++mi)
#pragma unroll
    for (int ni = 0; ni < 2; ++ni)
#pragma unroll
      for (int r = 0; r < 4; ++r) { acc0[mi][ni][r] = 0.f; acc1[mi][ni][r] = 0.f; }

#define STAGE1(kt, sl) do { int c_ = (kt) * BK;         \
    load_lds16(pA0 + c_,  &As[sl][s0 * 8]);             \
    load_lds16(pA1 + c_,  &As[sl][s1 * 8]);             \
    load_lds16(pB00 + c_, &B0s[sl][s0 * 8]);            \
    load_lds16(pB01 + c_, &B0s[sl][s1 * 8]);            \
    load_lds16(pB10 + c_, &B1s[sl][s0 * 8]);            \
    load_lds16(pB11 + c_, &B1s[sl][s1 * 8]); } while (0)

#define COMPUTE1(sl) do {                                                   \
    const unsigned short* ap = As[sl];                                      \
    const unsigned short* q0 = B0s[sl];                                     \
    const unsigned short* q1 = B1s[sl];                                     \
    bf16x8 a[2][4], b0[2][2], b1[2][2];                                     \
    _Pragma("unroll") for (int mi = 0; mi < 4; ++mi) {                      \
      a[0][mi] = *(const bf16x8*)(ap + (wm + mi * 16 + fr) * BK + co0);     \
      a[1][mi] = *(const bf16x8*)(ap + (wm + mi * 16 + fr) * BK + co1); }   \
    _Pragma("unroll") for (int ni = 0; ni < 2; ++ni) {                      \
      b0[0][ni] = *(const bf16x8*)(q0 + (wn + ni * 16 + fr) * BK + co0);    \
      b0[1][ni] = *(const bf16x8*)(q0 + (wn + ni * 16 + fr) * BK + co1);    \
      b1[0][ni] = *(const bf16x8*)(q1 + (wn + ni * 16 + fr) * BK + co0);    \
      b1[1][ni] = *(const bf16x8*)(q1 + (wn + ni * 16 + fr) * BK + co1); }  \
    __builtin_amdgcn_s_setprio(1);                                          \
    _Pragma("unroll") for (int kh = 0; kh < 2; ++kh)                        \
      _Pragma("unroll") for (int mi = 0; mi < 4; ++mi)                      \
        _Pragma("unroll") for (int ni = 0; ni < 2; ++ni) {                  \
          acc0[mi][ni] = __builtin_amdgcn_mfma_f32_16x16x32_bf16(a[kh][mi], b0[kh][ni], acc0[mi][ni], 0, 0, 0); \
          acc1[mi][ni] = __builtin_amdgcn_mfma_f32_16x16x32_bf16(a[kh][mi], b1[kh][ni], acc1[mi][ni], 0, 0, 0); } \
    __builtin_amdgcn_s_setprio(0); } while (0)

  STAGE1(0, 0);
  STAGE1(1, 1);
  int cur = 0, nxt = 2;
  for (int kt = 0; kt < NT1; ++kt) {
    if (kt < NT1 - 1) { VMW(6); } else { VMW(0); }   // slot kt landed (per wave)
    BARRIER();                                       // -> landed for ALL waves
    if (kt + 2 < NT1) STAGE1(kt + 2, nxt);           // overwrites slot read at kt-1
    COMPUTE1(cur);
    cur = (cur == 2) ? 0 : cur + 1;
    nxt = (nxt == 2) ? 0 : nxt + 1;
  }
#undef STAGE1
#undef COMPUTE1

  int n0 = nt * BN + wn;
#pragma unroll
  for (int mi = 0; mi < 4; ++mi) {
    int mloc = wm + mi * 16 + fq * 4;
#pragma unroll
    for (int ni = 0; ni < 2; ++ni) {
      int col = n0 + ni * 16 + fr;
#pragma unroll
      for (int r = 0; r < 4; ++r) {
        int mrow = mloc + r;
        if (mrow < mv) {
          float g = acc0[mi][ni][r];
          float hv = (g / (1.0f + expf(-g))) * acc1[mi][ni][r];
          H[(size_t)(gbase + mrow) * FDIM + col] = f2bf(hv);
        }
      }
    }
  }
}

// ---------------- GEMM2: O = H @ wo^T(stored [D][F]) ----------------
// 512 thr / 8 waves, 4-slot LDS ring (128 KB), prefetch depth 3, vmcnt(8) waits.

__global__ __launch_bounds__(512, 2) void k_gemm2(
    const unsigned short* __restrict__ H, const unsigned short* __restrict__ wot,
    const int* __restrict__ counts, const int* __restrict__ bases,
    unsigned short* __restrict__ O) {
  int b = blockIdx.x;
  int xcd = b & 7, j = b >> 3;
  int i8 = j & 7, grp = j >> 3;
  int G = grp * 8 + xcd;               // 0..511
  int e = G >> 6;
  int mt = G & 63;
  int nt = i8;                         // 0..7

  int cnt = counts[e];
  int m0 = mt * BM;
  if (m0 >= cnt) return;
  int mv = min(BM, cnt - m0);
  int gbase = bases[e] + m0;

  __shared__ __align__(16) unsigned short As[4][BM * BK];
  __shared__ __align__(16) unsigned short Bs[4][BN * BK];

  int t = threadIdx.x;
  int wid = t >> 6, lane = t & 63;
  int wm = (wid >> 2) * 64, wn = (wid & 3) * 32;
  int fr = lane & 15, fq = lane >> 4;
  int sw = fr & 7;
  int co0 = (fq ^ sw) * 8;
  int co1 = ((4 | fq) ^ sw) * 8;

  const unsigned short* bp = wot + ((size_t)e * DDIM + (size_t)nt * BN) * FDIM;

  int s0 = t, s1 = t + 512;
  int r0 = s0 >> 3, r1 = s1 >> 3;
  int o0 = ((s0 & 7) ^ (r0 & 7)) * 8, o1 = ((s1 & 7) ^ (r1 & 7)) * 8;
  const unsigned short* pA0 = H + (size_t)(gbase + min(r0, mv - 1)) * FDIM + o0;
  const unsigned short* pA1 = H + (size_t)(gbase + min(r1, mv - 1)) * FDIM + o1;
  const unsigned short* pB0 = bp + (size_t)r0 * FDIM + o0;
  const unsigned short* pB1 = bp + (size_t)r1 * FDIM + o1;

  f32x4 acc[4][2];
#pragma unroll
  for (int mi = 0; mi < 4; ++mi)
#pragma unroll
    for (int ni = 0; ni < 2; ++ni)
#pragma unroll
      for (int r = 0; r < 4; ++r) acc[mi][ni][r] = 0.f;

#define STAGE2(kt, sl) do { int c_ = (kt) * BK;         \
    load_lds16(pA0 + c_, &As[sl][s0 * 8]);              \
    load_lds16(pA1 + c_, &As[sl][s1 * 8]);              \
    load_lds16(pB0 + c_, &Bs[sl][s0 * 8]);              \
    load_lds16(pB1 + c_, &Bs[sl][s1 * 8]); } while (0)

#define COMPUTE2(sl) do {                                                   \
    const unsigned short* ap = As[sl];                                      \
    const unsigned short* qp = Bs[sl];                                      \
    bf16x8 a[2][4], bb[2][2];                                               \
    _Pragma("unroll") for (int mi = 0; mi < 4; ++mi) {                      \
      a[0][mi] = *(const bf16x8*)(ap + (wm + mi * 16 + fr) * BK + co0);     \
      a[1][mi] = *(const bf16x8*)(ap + (wm + mi * 16 + fr) * BK + co1); }   \
    _Pragma("unroll") for (int ni = 0; ni < 2; ++ni) {                      \
      bb[0][ni] = *(const bf16x8*)(qp + (wn + ni * 16 + fr) * BK + co0);    \
      bb[1][ni] = *(const bf16x8*)(qp + (wn + ni * 16 + fr) * BK + co1); }  \
    __builtin_amdgcn_s_setprio(1);                                          \
    _Pragma("unroll") for (int kh = 0; kh < 2; ++kh)                        \
      _Pragma("unroll") for (int mi = 0; mi < 4; ++mi)                      \
        _Pragma("unroll") for (int ni = 0; ni < 2; ++ni)                    \
          acc[mi][ni] = __builtin_amdgcn_mfma_f32_16x16x32_bf16(a[kh][mi], bb[kh][ni], acc[mi][ni], 0, 0, 0); \
    __builtin_amdgcn_s_setprio(0); } while (0)

  STAGE2(0, 0);
  STAGE2(1, 1);
  STAGE2(2, 2);
  for (int kt = 0; kt < NT2; ++kt) {
    if (kt <= NT2 - 3) { VMW(8); }
    else if (kt == NT2 - 2) { VMW(4); }
    else { VMW(0); }
    BARRIER();
    if (kt + 3 < NT2) STAGE2(kt + 3, (kt + 3) & 3);
    COMPUTE2(kt & 3);
  }
#undef STAGE2
#undef COMPUTE2

  int n0 = nt * BN + wn;
#pragma unroll
  for (int mi = 0; mi < 4; ++mi) {
    int mloc = wm + mi * 16 + fq * 4;
#pragma unroll
    for (int ni = 0; ni < 2; ++ni) {
      int col = n0 + ni * 16 + fr;
#pragma unroll
      for (int r = 0; r < 4; ++r) {
        int mrow = mloc + r;
        if (mrow < mv)
          O[(size_t)(gbase + mrow) * DDIM + col] = f2bf(acc[mi][ni][r]);
      }
    }
  }
}

// ---------------- combine ----------------

__global__ void k_combine(const unsigned short* __restrict__ O, const int* __restrict__ bases,
                          const int* __restrict__ tok_slot, const float* __restrict__ wgt_list,
                          float* __restrict__ out) {
  int t = blockIdx.x;
  int s0 = tok_slot[t * 2 + 0];
  int s1 = tok_slot[t * 2 + 1];
  int g0 = bases[s0 / CAP] + (s0 & (CAP - 1));
  int g1 = bases[s1 / CAP] + (s1 & (CAP - 1));
  float w0 = wgt_list[s0], w1 = wgt_list[s1];
  int d = threadIdx.x * 4;
  ushort4 a = *(const ushort4*)(O + (size_t)g0 * DDIM + d);
  ushort4 b = *(const ushort4*)(O + (size_t)g1 * DDIM + d);
  float4 r;
  r.x = w0 * bf2f(a.x) + w1 * bf2f(b.x);
  r.y = w0 * bf2f(a.y) + w1 * bf2f(b.y);
  r.z = w0 * bf2f(a.z) + w1 * bf2f(b.z);
  r.w = w0 * bf2f(a.w) + w1 * bf2f(b.w);
  *(float4*)(out + (size_t)t * DDIM + d) = r;
}

// ---------------- launch ----------------

extern "C" void kernel_launch(void* const* d_in, const int* in_sizes, int n_in,
                              void* d_out, int out_size, void* d_ws, size_t ws_size,
                              hipStream_t stream) {
  const float* x   = (const float*)d_in[0];
  const float* gw  = (const float*)d_in[1];
  const float* wi0 = (const float*)d_in[2];
  const float* wi1 = (const float*)d_in[3];
  const float* wo  = (const float*)d_in[4];
  float* out = (float*)d_out;

  char* p = (char*)d_ws;
  unsigned short* xb  = (unsigned short*)p; p += (size_t)TOKENS * DDIM * 2;
  unsigned short* w0t = (unsigned short*)p; p += (size_t)NEXP * FDIM * DDIM * 2;
  unsigned short* w1t = (unsigned short*)p; p += (size_t)NEXP * FDIM * DDIM * 2;
  unsigned short* wot = (unsigned short*)p; p += (size_t)NEXP * DDIM * FDIM * 2;
  unsigned short* H   = (unsigned short*)p; p += (size_t)2 * TOKENS * FDIM * 2;
  unsigned short* O   = (unsigned short*)p; p += (size_t)2 * TOKENS * DDIM * 2;
  int*   counts   = (int*)p; p += 256;
  int*   bases    = (int*)p; p += 256;
  int*   tok_list = (int*)p; p += (size_t)NEXP * CAP * 4;
  float* wgt_list = (float*)p; p += (size_t)NEXP * CAP * 4;
  int*   tok_slot = (int*)p; p += (size_t)TOKENS * 2 * 4;

  // weight transpose+convert
  k_tconv<<<dim3(FDIM / 128, DDIM / 32, NEXP), 256, 0, stream>>>(wi0, w0t, DDIM, FDIM);
  k_tconv<<<dim3(FDIM / 128, DDIM / 32, NEXP), 256, 0, stream>>>(wi1, w1t, DDIM, FDIM);
  k_tconv<<<dim3(DDIM / 128, FDIM / 32, NEXP), 256, 0, stream>>>(wo, wot, FDIM, DDIM);

  // gating + routing (also emits xb)
  k_zero<<<1, 64, 0, stream>>>(counts);
  k_gate<<<TOKENS / 4, 256, 0, stream>>>(x, gw, xb, counts, tok_list, wgt_list, tok_slot);
  k_scan<<<1, 64, 0, stream>>>(counts, bases);

  // expert MLP (ring-pipelined, counted-vmcnt GEMMs; BK=64, proven swizzle)
  k_gemm1<<<(FDIM / BN) * (CAP / BM) * NEXP, 512, 0, stream>>>(xb, w0t, w1t, counts, bases, tok_list, H);
  k_gemm2<<<(DDIM / BN) * (CAP / BM) * NEXP, 512, 0, stream>>>(H, wot, counts, bases, O);

  // weighted combine
  k_combine<<<TOKENS, 256, 0, stream>>>(O, bases, tok_slot, wgt_list, out);
}